// Round 1
// baseline (3227.699 us; speedup 1.0000x reference)
//
#include <hip/hip_runtime.h>
#include <math.h>

#define NB 64
#define NT 2048
#define NI 64
#define NS 128
#define NO 64

typedef float4 f4;

// Raw barrier: waits only LDS (lgkmcnt), NOT outstanding global stores/loads.
// Keeps the per-step H store + x prefetch in flight across the barrier.
__device__ __forceinline__ void bar_lds() {
    asm volatile("s_waitcnt lgkmcnt(0)" ::: "memory");
    __builtin_amdgcn_s_barrier();
}

// ---------------- sequential scan: one block per batch ----------------
// thread layout: r = tid>>1 (state row 0..127), half = tid&1 (k-slice)
// A[r][half*64..+64), B[r][half*32..+32), Wsel[r][half*32..+32) in VGPRs.
__global__ __launch_bounds__(256, 1) void scan_kernel(
    const float* __restrict__ x,     // [NB][NT][NI]
    const float* __restrict__ A,     // [NS][NS]
    const float* __restrict__ Bm,    // [NS][NI]
    const float* __restrict__ Wsel,  // [NS][NI]
    const float* __restrict__ bsel,  // [NS]
    const float* __restrict__ gamma, // [NS]
    const float* __restrict__ beta,  // [NS]
    float* __restrict__ H,           // ws [NB][NT][NS]
    float* __restrict__ meanx)       // ws [NB][NI]
{
    const int b    = blockIdx.x;
    const int tid  = threadIdx.x;
    const int r    = tid >> 1;
    const int half = tid & 1;
    const int wave = tid >> 6;
    const int lane = tid & 63;

    __shared__ __align__(16) float hbuf[NS];
    __shared__ float red[8];
    __shared__ float mx[4][NI];

    // ---- meanx prologue: mean over t of x[b,:,k] ----
    {
        const int k  = tid & 63;
        const int ts = tid >> 6;
        float s = 0.f;
        const float* xb = x + ((size_t)b * NT) * NI;
        #pragma unroll 8
        for (int t = ts; t < NT; t += 4)
            s += xb[(size_t)t * NI + k];
        mx[ts][k] = s;
        __syncthreads();
        if (tid < 64)
            meanx[b * NI + tid] =
                (mx[0][tid] + mx[1][tid] + mx[2][tid] + mx[3][tid]) * (1.0f / NT);
    }

    // ---- weights to registers ----
    float a_w[64], b_w[32], w_w[32];
    {
        const float* ap = A    + (size_t)r * NS + half * 64;
        #pragma unroll
        for (int j = 0; j < 64; ++j) a_w[j] = ap[j];
        const float* bp = Bm   + (size_t)r * NI + half * 32;
        const float* wp = Wsel + (size_t)r * NI + half * 32;
        #pragma unroll
        for (int j = 0; j < 32; ++j) { b_w[j] = bp[j]; w_w[j] = wp[j]; }
    }
    const float bs = bsel[r];
    const float ga = gamma[r];
    const float be = beta[r];

    if (tid < NS) hbuf[tid] = 0.f;
    float h_r = 0.f;

    // x prefetch double-buffer (each thread needs x[b][t][half*32..+32))
    f4 xcur[8], xnxt[8];
    const float* xbase = x + ((size_t)b * NT) * NI + half * 32;
    {
        const f4* p0 = (const f4*)(xbase);
        const f4* p1 = (const f4*)(xbase + NI);
        #pragma unroll
        for (int q = 0; q < 8; ++q) { xcur[q] = p0[q]; xnxt[q] = p1[q]; }
    }

    float* Hb = H + ((size_t)b * NT) * NS + r;

    __syncthreads();  // hbuf init visible

    auto step = [&](int t, f4* xb_) {
        // --- dots against old h (LDS broadcast) and x_t (regs) ---
        float a0 = 0.f, a1 = 0.f, a2 = 0.f, a3 = 0.f;
        const f4* hp = (const f4*)(hbuf + half * 64);
        #pragma unroll
        for (int q = 0; q < 16; ++q) {
            f4 hv = hp[q];
            a0 = fmaf(a_w[4*q+0], hv.x, a0);
            a1 = fmaf(a_w[4*q+1], hv.y, a1);
            a2 = fmaf(a_w[4*q+2], hv.z, a2);
            a3 = fmaf(a_w[4*q+3], hv.w, a3);
        }
        float u0 = 0.f, u1 = 0.f, u2 = 0.f, u3 = 0.f;
        float g0 = 0.f, g1 = 0.f, g2 = 0.f, g3 = 0.f;
        #pragma unroll
        for (int q = 0; q < 8; ++q) {
            f4 xv = xb_[q];
            u0 = fmaf(b_w[4*q+0], xv.x, u0);
            u1 = fmaf(b_w[4*q+1], xv.y, u1);
            u2 = fmaf(b_w[4*q+2], xv.z, u2);
            u3 = fmaf(b_w[4*q+3], xv.w, u3);
            g0 = fmaf(w_w[4*q+0], xv.x, g0);
            g1 = fmaf(w_w[4*q+1], xv.y, g1);
            g2 = fmaf(w_w[4*q+2], xv.z, g2);
            g3 = fmaf(w_w[4*q+3], xv.w, g3);
        }
        float dA = (a0 + a1) + (a2 + a3);
        float dB = (u0 + u1) + (u2 + u3);
        float dW = (g0 + g1) + (g2 + g3);
        dA += __shfl_xor(dA, 1);
        dB += __shfl_xor(dB, 1);
        dW += __shfl_xor(dW, 1);

        float z    = dW + bs;
        float gate = 1.0f / (1.0f + expf(-z));
        float hn   = dA + dB;
        float hm   = gate * hn + (1.0f - gate) * h_r;   // literal reference form

        // --- LayerNorm over 128 rows (each duplicated x2 across lane pairs) ---
        float s = hm, s2 = hm * hm;
        #pragma unroll
        for (int d = 1; d < 64; d <<= 1) {
            s  += __shfl_xor(s, d);
            s2 += __shfl_xor(s2, d);
        }
        if (lane == 0) { red[wave] = s; red[4 + wave] = s2; }
        bar_lds();
        float S  = (red[0] + red[1]) + (red[2] + red[3]);
        float S2 = (red[4] + red[5]) + (red[6] + red[7]);
        float mean = S * (1.0f / 256.0f);                 // /2 dup /128 rows
        float var  = S2 * (1.0f / 256.0f) - mean * mean;
        float rstd = 1.0f / sqrtf(var + 1e-5f);
        float hl   = (hm - mean) * rstd * ga + be;
        h_r = hl;
        if (half == 0) {
            hbuf[r] = hl;
            Hb[(size_t)t * NS] = hl;   // fire-and-forget store (not drained)
        }
        // prefetch x for t+2 (overwrites this step's buffer after last use)
        if (t + 2 < NT) {
            const f4* p = (const f4*)(xbase + (size_t)(t + 2) * NI);
            #pragma unroll
            for (int q = 0; q < 8; ++q) xb_[q] = p[q];
        }
        bar_lds();
    };

    for (int t = 0; t < NT; t += 2) {
        step(t,     xcur);
        step(t + 1, xnxt);
    }
}

// ---------------- Y + statistics: grid = NB x 16 chunks of 128 t ----------------
// thread: o = tid&63 (output col), tg = tid>>6 owns contiguous t-range of 32.
__global__ __launch_bounds__(256, 1) void y_stats_kernel(
    const float* __restrict__ H,    // [NB][NT][NS]
    const float* __restrict__ x,    // [NB][NT][NI]
    const float* __restrict__ Cm,   // [NO][NS]
    const float* __restrict__ Dm,   // [NO][NI]
    float* __restrict__ SY,         // [NB][NO]
    float* __restrict__ SYY,        // [NB][NO]
    float* __restrict__ nsum,       // scalar
    float* __restrict__ dsum,       // scalar
    float* __restrict__ outFinal)   // d_out[0..4095]
{
    const int b     = blockIdx.x >> 4;
    const int chunk = blockIdx.x & 15;
    const int tid   = threadIdx.x;
    const int o     = tid & 63;
    const int tg    = tid >> 6;

    float c_w[128];
    {
        const f4* cp = (const f4*)(Cm + (size_t)o * NS);
        #pragma unroll
        for (int q = 0; q < 32; ++q) {
            f4 v = cp[q];
            c_w[4*q+0] = v.x; c_w[4*q+1] = v.y; c_w[4*q+2] = v.z; c_w[4*q+3] = v.w;
        }
    }
    float d_w[64];
    {
        const f4* dp = (const f4*)(Dm + (size_t)o * NI);
        #pragma unroll
        for (int q = 0; q < 16; ++q) {
            f4 v = dp[q];
            d_w[4*q+0] = v.x; d_w[4*q+1] = v.y; d_w[4*q+2] = v.z; d_w[4*q+3] = v.w;
        }
    }

    const int t0 = chunk * 128 + tg * 32;
    const float* Hb = H + ((size_t)b * NT) * NS;
    const float* xb = x + ((size_t)b * NT) * NI;

    auto yrow = [&](int t) -> float {
        const f4* hp = (const f4*)(Hb + (size_t)t * NS);
        const f4* xp = (const f4*)(xb + (size_t)t * NI);
        float y0 = 0.f, y1 = 0.f, y2 = 0.f, y3 = 0.f;
        #pragma unroll
        for (int q = 0; q < 32; ++q) {
            f4 hv = hp[q];
            y0 = fmaf(c_w[4*q+0], hv.x, y0);
            y1 = fmaf(c_w[4*q+1], hv.y, y1);
            y2 = fmaf(c_w[4*q+2], hv.z, y2);
            y3 = fmaf(c_w[4*q+3], hv.w, y3);
        }
        #pragma unroll
        for (int q = 0; q < 16; ++q) {
            f4 xv = xp[q];
            y0 = fmaf(d_w[4*q+0], xv.x, y0);
            y1 = fmaf(d_w[4*q+1], xv.y, y1);
            y2 = fmaf(d_w[4*q+2], xv.z, y2);
            y3 = fmaf(d_w[4*q+3], xv.w, y3);
        }
        return (y0 + y1) + (y2 + y3);
    };

    float yprev = 0.f;
    if (t0 > 0) yprev = yrow(t0 - 1);   // halo row for diff

    float sy = 0.f, syy = 0.f, na = 0.f, da = 0.f;
    for (int i = 0; i < 32; ++i) {
        const int t = t0 + i;
        float y = yrow(t);
        sy  += y;
        syy += y * y;
        float n2 = y * y;
        #pragma unroll
        for (int d = 1; d < 64; d <<= 1) n2 += __shfl_xor(n2, d);
        na += sqrtf(n2);
        if (t > 0) {
            float df = y - yprev;
            float d2 = df * df;
            #pragma unroll
            for (int d = 1; d < 64; d <<= 1) d2 += __shfl_xor(d2, d);
            da += sqrtf(d2);
        }
        yprev = y;
        if (t == NT - 1) outFinal[b * NO + o] = y;
    }
    atomicAdd(&SY[b * NO + o], sy);
    atomicAdd(&SYY[b * NO + o], syy);
    if (o == 0) { atomicAdd(nsum, na); atomicAdd(dsum, da); }
}

// ---------------- finalize scalars ----------------
__global__ __launch_bounds__(256) void finalize_kernel(
    const float* __restrict__ Wsel,
    const float* __restrict__ bsel,
    const float* __restrict__ meanx,
    const float* __restrict__ SY,
    const float* __restrict__ SYY,
    const float* __restrict__ nsum,
    const float* __restrict__ dsum,
    float* __restrict__ out)
{
    const int tid  = threadIdx.x;
    const int wave = tid >> 6;
    const int lane = tid & 63;
    __shared__ float rs[8];

    // selection_activity: 64x128 logits, K=64
    float accsel = 0.f;
    for (int idx = tid; idx < NB * NS; idx += 256) {
        int bb = idx >> 7;
        int s  = idx & 127;
        float z = bsel[s];
        const float* mp = meanx + bb * NI;
        const float* wp = Wsel  + (size_t)s * NI;
        #pragma unroll 8
        for (int k = 0; k < NI; ++k) z = fmaf(mp[k], wp[k], z);
        accsel += 1.0f / (1.0f + expf(-z));
    }
    // state_stability: std over t, ddof=1, per (b,o)
    float accss = 0.f;
    for (int idx = tid; idx < NB * NO; idx += 256) {
        float s1 = SY[idx], s2 = SYY[idx];
        float var = (s2 - s1 * s1 * (1.0f / NT)) * (1.0f / (NT - 1));
        accss += sqrtf(fmaxf(var, 0.0f));
    }
    #pragma unroll
    for (int d = 1; d < 64; d <<= 1) {
        accsel += __shfl_xor(accsel, d);
        accss  += __shfl_xor(accss, d);
    }
    if (lane == 0) { rs[wave] = accsel; rs[4 + wave] = accss; }
    __syncthreads();
    if (tid == 0) {
        float sel = (rs[0] + rs[1] + rs[2] + rs[3]) / (float)(NB * NS);
        float ss  = (rs[4] + rs[5] + rs[6] + rs[7]) / (float)(NB * NO);
        float tc  = 1.0f / (1.0f + dsum[0] / (float)(NB * (NT - 1)));
        float sm  = nsum[0] / (float)(NB * NT);
        out[4096] = tc;
        out[4097] = sm;
        out[4098] = sel;
        out[4099] = ss;
    }
}

extern "C" void kernel_launch(void* const* d_in, const int* in_sizes, int n_in,
                              void* d_out, int out_size, void* d_ws, size_t ws_size,
                              hipStream_t stream)
{
    (void)in_sizes; (void)n_in; (void)out_size; (void)ws_size;
    const float* x     = (const float*)d_in[0];
    const float* A     = (const float*)d_in[1];
    const float* Bm    = (const float*)d_in[2];
    const float* Cm    = (const float*)d_in[3];
    const float* Dm    = (const float*)d_in[4];
    const float* Wsel  = (const float*)d_in[5];
    const float* bsel  = (const float*)d_in[6];
    const float* gamma = (const float*)d_in[7];
    const float* beta  = (const float*)d_in[8];
    float* out = (float*)d_out;

    char* ws = (char*)d_ws;
    size_t off = 0;
    float* H = (float*)(ws + off);      off += (size_t)NB * NT * NS * sizeof(float); // 64 MB
    char*  zbase = ws + off;
    float* SY    = (float*)(ws + off);  off += NB * NO * sizeof(float);
    float* SYY   = (float*)(ws + off);  off += NB * NO * sizeof(float);
    float* meanx = (float*)(ws + off);  off += NB * NI * sizeof(float);
    float* nsum  = (float*)(ws + off);  off += sizeof(float);
    float* dsum  = (float*)(ws + off);  off += sizeof(float);
    size_t zbytes = (size_t)((char*)(dsum + 1) - zbase);

    hipMemsetAsync(zbase, 0, zbytes, stream);
    scan_kernel<<<NB, 256, 0, stream>>>(x, A, Bm, Wsel, bsel, gamma, beta, H, meanx);
    y_stats_kernel<<<NB * 16, 256, 0, stream>>>(H, x, Cm, Dm, SY, SYY, nsum, dsum, out);
    finalize_kernel<<<1, 256, 0, stream>>>(Wsel, bsel, meanx, SY, SYY, nsum, dsum, out);
}

// Round 2
// 2333.816 us; speedup vs baseline: 1.3830x; 1.3830x over previous
//
#include <hip/hip_runtime.h>
#include <math.h>

#define NB 64
#define NT 2048
#define NI 64
#define NS 128
#define NO 64

typedef float4 f4;

// ---------- fast cross-lane helpers (VALU DPP, not DS pipe) ----------
template<int CTRL>
__device__ __forceinline__ float dpp_add(float v) {
    int t = __builtin_amdgcn_update_dpp(0, __float_as_int(v), CTRL, 0xF, 0xF, true);
    return v + __int_as_float(t);
}
// combine across lane^1 (quad_perm [1,0,3,2]) and lane^2 (quad_perm [2,3,0,1])
__device__ __forceinline__ float qxor1(float v) { return dpp_add<0xB1>(v); }
__device__ __forceinline__ float qxor2(float v) { return dpp_add<0x4E>(v); }
// full wave-64 sum; result valid in lane 63 only (row_shr cascade + bcast15/31)
__device__ __forceinline__ float wave_sum63(float v) {
    v = dpp_add<0x111>(v);
    v = dpp_add<0x112>(v);
    v = dpp_add<0x114>(v);
    v = dpp_add<0x118>(v);
    v = dpp_add<0x142>(v);
    v = dpp_add<0x143>(v);
    return v;
}

__device__ __forceinline__ float sigmoidf_fast(float z) {
    float e = __builtin_amdgcn_exp2f(z * -1.442695041f);
    return __builtin_amdgcn_rcpf(1.0f + e);
}

__device__ __forceinline__ void bar_lds() {
    asm volatile("s_waitcnt lgkmcnt(0)" ::: "memory");
    __builtin_amdgcn_s_barrier();
}

// =====================================================================
// K1: sequential scan. One block (256 thr) per batch.
// thread: q = tid&3 (K-quarter), rr = tid>>2; owns rows r0=rr, r1=rr+64.
// State kept as RAW pre-LN m; LN folded into A via gamma/beta.
// Single barrier per step; parity double-buffered LDS.
// =====================================================================
__global__ __launch_bounds__(256, 1) void scan_kernel(
    const float* __restrict__ x,     // [NB][NT][NI]
    const float* __restrict__ A,     // [NS][NS]
    const float* __restrict__ Bm,    // [NS][NI]
    const float* __restrict__ Wsel,  // [NS][NI]
    const float* __restrict__ bsel,  // [NS]
    const float* __restrict__ gamma, // [NS]
    const float* __restrict__ beta,  // [NS]
    float* __restrict__ H,           // ws [NB][NT][NS]  raw m
    float* __restrict__ musig)       // ws [NB][NT] float2 (mu, rstd)
{
    const int b    = blockIdx.x;
    const int tid  = threadIdx.x;
    const int q    = tid & 3;
    const int rr   = tid >> 2;      // 0..63
    const int r0   = rr;
    const int r1   = rr + 64;
    const int lane = tid & 63;
    const int wave = tid >> 6;

    // padded: quarter q lives at float offset q*36 (banks disjoint per q)
    __shared__ __align__(16) float hbuf[2][148];
    __shared__ __align__(16) float red[2][8];

    // ---- weights: A gamma-folded + fold scalars ----
    float a0w[32], a1w[32];
    float sAg0 = 0.f, sAg1 = 0.f, aB0 = 0.f, aB1 = 0.f;
    {
        const f4* ga = (const f4*)(gamma + q * 32);
        const f4* bb = (const f4*)(beta  + q * 32);
        const f4* A0 = (const f4*)(A + (size_t)r0 * NS + q * 32);
        const f4* A1 = (const f4*)(A + (size_t)r1 * NS + q * 32);
        #pragma unroll
        for (int j = 0; j < 8; ++j) {
            f4 g = ga[j], be_ = bb[j], v0 = A0[j], v1 = A1[j];
            float f00 = v0.x * g.x, f01 = v0.y * g.y, f02 = v0.z * g.z, f03 = v0.w * g.w;
            float f10 = v1.x * g.x, f11 = v1.y * g.y, f12 = v1.z * g.z, f13 = v1.w * g.w;
            a0w[4*j+0] = f00; a0w[4*j+1] = f01; a0w[4*j+2] = f02; a0w[4*j+3] = f03;
            a1w[4*j+0] = f10; a1w[4*j+1] = f11; a1w[4*j+2] = f12; a1w[4*j+3] = f13;
            sAg0 += (f00 + f01) + (f02 + f03);
            sAg1 += (f10 + f11) + (f12 + f13);
            aB0 = fmaf(v0.x, be_.x, aB0); aB0 = fmaf(v0.y, be_.y, aB0);
            aB0 = fmaf(v0.z, be_.z, aB0); aB0 = fmaf(v0.w, be_.w, aB0);
            aB1 = fmaf(v1.x, be_.x, aB1); aB1 = fmaf(v1.y, be_.y, aB1);
            aB1 = fmaf(v1.z, be_.z, aB1); aB1 = fmaf(v1.w, be_.w, aB1);
        }
        sAg0 = qxor2(qxor1(sAg0));  sAg1 = qxor2(qxor1(sAg1));
        aB0  = qxor2(qxor1(aB0));   aB1  = qxor2(qxor1(aB1));
    }
    float b0w[16], b1w[16], w0w[16], w1w[16];
    {
        const f4* B0 = (const f4*)(Bm   + (size_t)r0 * NI + q * 16);
        const f4* B1 = (const f4*)(Bm   + (size_t)r1 * NI + q * 16);
        const f4* W0 = (const f4*)(Wsel + (size_t)r0 * NI + q * 16);
        const f4* W1 = (const f4*)(Wsel + (size_t)r1 * NI + q * 16);
        #pragma unroll
        for (int j = 0; j < 4; ++j) {
            f4 v;
            v = B0[j]; b0w[4*j+0]=v.x; b0w[4*j+1]=v.y; b0w[4*j+2]=v.z; b0w[4*j+3]=v.w;
            v = B1[j]; b1w[4*j+0]=v.x; b1w[4*j+1]=v.y; b1w[4*j+2]=v.z; b1w[4*j+3]=v.w;
            v = W0[j]; w0w[4*j+0]=v.x; w0w[4*j+1]=v.y; w0w[4*j+2]=v.z; w0w[4*j+3]=v.w;
            v = W1[j]; w1w[4*j+0]=v.x; w1w[4*j+1]=v.y; w1w[4*j+2]=v.z; w1w[4*j+3]=v.w;
        }
    }
    const float bs0 = bsel[r0],  bs1 = bsel[r1];
    const float gm0 = gamma[r0], gm1 = gamma[r1];
    const float bt0 = beta[r0],  bt1 = beta[r1];

    const float* xq = x + ((size_t)b * NT) * NI + q * 16;
    f4 xb0[4], xb1[4];
    #pragma unroll
    for (int j = 0; j < 4; ++j) xb0[j] = ((const f4*)xq)[j];        // x_0
    #pragma unroll
    for (int j = 0; j < 4; ++j) xb1[j] = ((const f4*)(xq + NI))[j]; // x_1

    // x-projections for one timestep (slice dot + quad combines)
    float z0p, z1p, dB0p, dB1p;
    auto xdots = [&](const f4 (&xv)[4]) {
        float p0 = 0.f, p1 = 0.f, pw0 = 0.f, pw1 = 0.f;
        #pragma unroll
        for (int j = 0; j < 4; ++j) {
            f4 v = xv[j];
            p0  = fmaf(b0w[4*j+0], v.x, p0);  p0  = fmaf(b0w[4*j+1], v.y, p0);
            p0  = fmaf(b0w[4*j+2], v.z, p0);  p0  = fmaf(b0w[4*j+3], v.w, p0);
            p1  = fmaf(b1w[4*j+0], v.x, p1);  p1  = fmaf(b1w[4*j+1], v.y, p1);
            p1  = fmaf(b1w[4*j+2], v.z, p1);  p1  = fmaf(b1w[4*j+3], v.w, p1);
            pw0 = fmaf(w0w[4*j+0], v.x, pw0); pw0 = fmaf(w0w[4*j+1], v.y, pw0);
            pw0 = fmaf(w0w[4*j+2], v.z, pw0); pw0 = fmaf(w0w[4*j+3], v.w, pw0);
            pw1 = fmaf(w1w[4*j+0], v.x, pw1); pw1 = fmaf(w1w[4*j+1], v.y, pw1);
            pw1 = fmaf(w1w[4*j+2], v.z, pw1); pw1 = fmaf(w1w[4*j+3], v.w, pw1);
        }
        dB0p = qxor2(qxor1(p0));
        dB1p = qxor2(qxor1(p1));
        z0p  = qxor2(qxor1(pw0)) + bs0;
        z1p  = qxor2(qxor1(pw1)) + bs1;
    };

    float* Hb = H + ((size_t)b * NT) * NS;
    float2* musb = (float2*)musig + (size_t)b * NT;

    // ---- peel t = 0 : h_prev = 0, dA = 0 ----
    float mp0, mp1;  // raw m for own rows (prev step)
    xdots(xb0);
    {
        float g0 = sigmoidf_fast(z0p), g1 = sigmoidf_fast(z1p);
        mp0 = g0 * dB0p;
        mp1 = g1 * dB1p;
        if (q == 0) {
            hbuf[0][((r0 >> 5) * 36) + (r0 & 31)] = mp0;
            hbuf[0][((r1 >> 5) * 36) + (r1 & 31)] = mp1;
            Hb[r0] = mp0; Hb[r1] = mp1;
        }
        float s  = wave_sum63(mp0 + mp1);
        float s2 = wave_sum63(fmaf(mp0, mp0, mp1 * mp1));
        if (lane == 63) { red[0][wave] = s; red[0][4 + wave] = s2; }
    }
    xdots(xb1);  // pending z/dB for t=1
    #pragma unroll
    for (int j = 0; j < 4; ++j) xb0[j] = ((const f4*)(xq + 2 * NI))[j]; // x_2
    bar_lds();

    // ---- main step body: parIn/parOut compile-time via call sites ----
    auto body = [&](int t, int parIn, int parOut, f4 (&xUse)[4], f4 (&xPre)[4]) {
        // 1. prefetch x_{t+2}
        if (t + 2 < NT) {
            const f4* px = (const f4*)(xq + (size_t)(t + 2) * NI);
            #pragma unroll
            for (int j = 0; j < 4; ++j) xPre[j] = px[j];
        }
        // 2. stats of m_{t-1}
        f4 sr  = *((const f4*)&red[parIn][0]);
        f4 sr2 = *((const f4*)&red[parIn][4]);
        float S  = (sr.x + sr.y) + (sr.z + sr.w);
        float S2 = (sr2.x + sr2.y) + (sr2.z + sr2.w);
        float mu   = S * (1.0f / 512.0f);                // 4x dup, 128 rows
        float var  = fmaf(S2, 1.0f / 512.0f, -mu * mu);
        float rstd = 1.0f / sqrtf(var + 1e-5f);
        // 3. A-dots on raw m_{t-1} (gamma-folded)
        const f4* hp = (const f4*)&hbuf[parIn][q * 36];
        float d0 = 0.f, e0 = 0.f, d1 = 0.f, e1 = 0.f;
        #pragma unroll
        for (int j = 0; j < 8; ++j) {
            f4 v = hp[j];
            d0 = fmaf(a0w[4*j+0], v.x, d0); e0 = fmaf(a0w[4*j+1], v.y, e0);
            d0 = fmaf(a0w[4*j+2], v.z, d0); e0 = fmaf(a0w[4*j+3], v.w, e0);
            d1 = fmaf(a1w[4*j+0], v.x, d1); e1 = fmaf(a1w[4*j+1], v.y, e1);
            d1 = fmaf(a1w[4*j+2], v.z, d1); e1 = fmaf(a1w[4*j+3], v.w, e1);
        }
        float dAm0 = qxor2(qxor1(d0 + e0));
        float dAm1 = qxor2(qxor1(d1 + e1));
        float dA0 = fmaf(rstd, fmaf(-mu, sAg0, dAm0), aB0);
        float dA1 = fmaf(rstd, fmaf(-mu, sAg1, dAm1), aB1);
        // 4. own-row prev LN value
        float hpl0 = fmaf((mp0 - mu) * rstd, gm0, bt0);
        float hpl1 = fmaf((mp1 - mu) * rstd, gm1, bt1);
        // 5. gate / mix -> m_t
        float g0 = sigmoidf_fast(z0p), g1 = sigmoidf_fast(z1p);
        float hn0 = dA0 + dB0p, hn1 = dA1 + dB1p;
        float m0 = fmaf(g0, hn0 - hpl0, hpl0);
        float m1 = fmaf(g1, hn1 - hpl1, hpl1);
        // 6. publish state (LDS + fire-and-forget global)
        if (q == 0) {
            hbuf[parOut][((r0 >> 5) * 36) + (r0 & 31)] = m0;
            hbuf[parOut][((r1 >> 5) * 36) + (r1 & 31)] = m1;
            float* hw = Hb + (size_t)t * NS;
            hw[r0] = m0; hw[r1] = m1;
        }
        // 7. wave stats reduce of m_t
        float s  = wave_sum63(m0 + m1);
        float s2 = wave_sum63(fmaf(m0, m0, m1 * m1));
        if (lane == 63) { red[parOut][wave] = s; red[parOut][4 + wave] = s2; }
        // 8. musig for t-1
        if (tid == 0) musb[t - 1] = make_float2(mu, rstd);
        mp0 = m0; mp1 = m1;
        // 9. x-projections for t+1
        if (t + 1 < NT) xdots(xUse);
        // 10. single barrier
        bar_lds();
    };

    for (int t = 1; t + 1 < NT; t += 2) {
        body(t,     0, 1, xb0, xb1);
        body(t + 1, 1, 0, xb1, xb0);
    }
    body(NT - 1, 0, 1, xb0, xb1);

    // epilogue: stats of m_{NT-1}
    {
        f4 sr  = *((const f4*)&red[1][0]);
        f4 sr2 = *((const f4*)&red[1][4]);
        float S  = (sr.x + sr.y) + (sr.z + sr.w);
        float S2 = (sr2.x + sr2.y) + (sr2.z + sr2.w);
        float mu   = S * (1.0f / 512.0f);
        float var  = fmaf(S2, 1.0f / 512.0f, -mu * mu);
        float rstd = 1.0f / sqrtf(var + 1e-5f);
        if (tid == 0) musb[NT - 1] = make_float2(mu, rstd);
    }
}

// =====================================================================
// K2: y + statistics, fully parallel. grid = NB x 32 chunks of 64 t.
// y = rstd*(dot(C*gamma, m) - mu*sum(C*gamma)) + dot(C,beta) + dot(D,x)
// =====================================================================
#define CHUNKS 32
#define TCH (NT / CHUNKS)   // 64

__global__ __launch_bounds__(256, 1) void y_stats_kernel(
    const float* __restrict__ H,
    const float* __restrict__ x,
    const float* __restrict__ Cm,
    const float* __restrict__ Dm,
    const float* __restrict__ gamma,
    const float* __restrict__ beta,
    const float* __restrict__ musig,
    float* __restrict__ SY,
    float* __restrict__ SYY,
    float* __restrict__ meanx,     // raw sums (divided in K3)
    float* __restrict__ nsum,
    float* __restrict__ dsum,
    float* __restrict__ outFinal)
{
    const int b     = blockIdx.x >> 5;
    const int chunk = blockIdx.x & 31;
    const int tid   = threadIdx.x;
    const int o     = tid & 63;
    const int tg    = tid >> 6;

    float c_w[128]; float sCg = 0.f, cB = 0.f;
    {
        const f4* cp = (const f4*)(Cm + (size_t)o * NS);
        const f4* gp = (const f4*)gamma;
        const f4* bp = (const f4*)beta;
        #pragma unroll
        for (int j = 0; j < 32; ++j) {
            f4 v = cp[j], g = gp[j], be = bp[j];
            float f0 = v.x * g.x, f1 = v.y * g.y, f2 = v.z * g.z, f3 = v.w * g.w;
            c_w[4*j+0] = f0; c_w[4*j+1] = f1; c_w[4*j+2] = f2; c_w[4*j+3] = f3;
            sCg += (f0 + f1) + (f2 + f3);
            cB = fmaf(v.x, be.x, cB); cB = fmaf(v.y, be.y, cB);
            cB = fmaf(v.z, be.z, cB); cB = fmaf(v.w, be.w, cB);
        }
    }
    float d_w[64];
    {
        const f4* dp = (const f4*)(Dm + (size_t)o * NI);
        #pragma unroll
        for (int j = 0; j < 16; ++j) {
            f4 v = dp[j];
            d_w[4*j+0] = v.x; d_w[4*j+1] = v.y; d_w[4*j+2] = v.z; d_w[4*j+3] = v.w;
        }
    }

    const float* Hb = H + ((size_t)b * NT) * NS;
    const float* xb = x + ((size_t)b * NT) * NI;
    const float2* msb = (const float2*)musig + (size_t)b * NT;

    // meanx partial (k = o), 16 t's per thread
    {
        const int t0 = chunk * TCH + tg * 16;
        float s = 0.f;
        const float* xk = xb + o;
        #pragma unroll 4
        for (int i = 0; i < 16; ++i) s += xk[(size_t)(t0 + i) * NI];
        atomicAdd(&meanx[b * NI + o], s);
    }

    auto yrow = [&](int t) -> float {
        const f4* hp = (const f4*)(Hb + (size_t)t * NS);
        const f4* xp = (const f4*)(xb + (size_t)t * NI);
        float2 ms = msb[t];
        float y0 = 0.f, y1 = 0.f, y2 = 0.f, y3 = 0.f;
        #pragma unroll
        for (int j = 0; j < 32; ++j) {
            f4 hv = hp[j];
            y0 = fmaf(c_w[4*j+0], hv.x, y0);
            y1 = fmaf(c_w[4*j+1], hv.y, y1);
            y2 = fmaf(c_w[4*j+2], hv.z, y2);
            y3 = fmaf(c_w[4*j+3], hv.w, y3);
        }
        float hdot = (y0 + y1) + (y2 + y3);
        float x0 = 0.f, x1 = 0.f, x2 = 0.f, x3 = 0.f;
        #pragma unroll
        for (int j = 0; j < 16; ++j) {
            f4 xv = xp[j];
            x0 = fmaf(d_w[4*j+0], xv.x, x0);
            x1 = fmaf(d_w[4*j+1], xv.y, x1);
            x2 = fmaf(d_w[4*j+2], xv.z, x2);
            x3 = fmaf(d_w[4*j+3], xv.w, x3);
        }
        float xdot = (x0 + x1) + (x2 + x3);
        return fmaf(ms.y, fmaf(-ms.x, sCg, hdot), cB + xdot);
    };

    const int t0 = chunk * TCH + tg * 16;
    float yprev = 0.f;
    if (t0 > 0) yprev = yrow(t0 - 1);

    float sy = 0.f, syy = 0.f, na = 0.f, da = 0.f;
    for (int i = 0; i < 16; ++i) {
        const int t = t0 + i;
        float y = yrow(t);
        sy  += y;
        syy += y * y;
        float n2 = y * y;
        #pragma unroll
        for (int d = 1; d < 64; d <<= 1) n2 += __shfl_xor(n2, d);
        na += sqrtf(n2);
        if (t > 0) {
            float df = y - yprev;
            float d2 = df * df;
            #pragma unroll
            for (int d = 1; d < 64; d <<= 1) d2 += __shfl_xor(d2, d);
            da += sqrtf(d2);
        }
        yprev = y;
        if (t == NT - 1) outFinal[b * NO + o] = y;
    }
    atomicAdd(&SY[b * NO + o], sy);
    atomicAdd(&SYY[b * NO + o], syy);
    if (o == 0) { atomicAdd(nsum, na); atomicAdd(dsum, da); }
}

// =====================================================================
// K3: finalize scalars
// =====================================================================
__global__ __launch_bounds__(256) void finalize_kernel(
    const float* __restrict__ Wsel,
    const float* __restrict__ bsel,
    const float* __restrict__ meanx,   // raw sums
    const float* __restrict__ SY,
    const float* __restrict__ SYY,
    const float* __restrict__ nsum,
    const float* __restrict__ dsum,
    float* __restrict__ out)
{
    const int tid  = threadIdx.x;
    const int wave = tid >> 6;
    const int lane = tid & 63;
    __shared__ float rs[8];

    float accsel = 0.f;
    for (int idx = tid; idx < NB * NS; idx += 256) {
        int bb = idx >> 7;
        int s  = idx & 127;
        const float* mp = meanx + bb * NI;
        const float* wp = Wsel  + (size_t)s * NI;
        float dot = 0.f;
        #pragma unroll 8
        for (int k = 0; k < NI; ++k) dot = fmaf(mp[k], wp[k], dot);
        float z = fmaf(dot, 1.0f / NT, bsel[s]);
        accsel += 1.0f / (1.0f + expf(-z));
    }
    float accss = 0.f;
    for (int idx = tid; idx < NB * NO; idx += 256) {
        float s1 = SY[idx], s2 = SYY[idx];
        float var = (s2 - s1 * s1 * (1.0f / NT)) * (1.0f / (NT - 1));
        accss += sqrtf(fmaxf(var, 0.0f));
    }
    #pragma unroll
    for (int d = 1; d < 64; d <<= 1) {
        accsel += __shfl_xor(accsel, d);
        accss  += __shfl_xor(accss, d);
    }
    if (lane == 0) { rs[wave] = accsel; rs[4 + wave] = accss; }
    __syncthreads();
    if (tid == 0) {
        float sel = (rs[0] + rs[1] + rs[2] + rs[3]) / (float)(NB * NS);
        float ss  = (rs[4] + rs[5] + rs[6] + rs[7]) / (float)(NB * NO);
        float tc  = 1.0f / (1.0f + dsum[0] / (float)(NB * (NT - 1)));
        float sm  = nsum[0] / (float)(NB * NT);
        out[4096] = tc;
        out[4097] = sm;
        out[4098] = sel;
        out[4099] = ss;
    }
}

extern "C" void kernel_launch(void* const* d_in, const int* in_sizes, int n_in,
                              void* d_out, int out_size, void* d_ws, size_t ws_size,
                              hipStream_t stream)
{
    (void)in_sizes; (void)n_in; (void)out_size; (void)ws_size;
    const float* x     = (const float*)d_in[0];
    const float* A     = (const float*)d_in[1];
    const float* Bm    = (const float*)d_in[2];
    const float* Cm    = (const float*)d_in[3];
    const float* Dm    = (const float*)d_in[4];
    const float* Wsel  = (const float*)d_in[5];
    const float* bsel  = (const float*)d_in[6];
    const float* gamma = (const float*)d_in[7];
    const float* beta  = (const float*)d_in[8];
    float* out = (float*)d_out;

    char* ws = (char*)d_ws;
    size_t off = 0;
    float* H     = (float*)(ws + off); off += (size_t)NB * NT * NS * sizeof(float); // 64 MB
    float* musig = (float*)(ws + off); off += (size_t)NB * NT * 2 * sizeof(float);  // 1 MB
    char*  zbase = ws + off;
    float* SY    = (float*)(ws + off); off += NB * NO * sizeof(float);
    float* SYY   = (float*)(ws + off); off += NB * NO * sizeof(float);
    float* meanx = (float*)(ws + off); off += NB * NI * sizeof(float);
    float* nsum  = (float*)(ws + off); off += sizeof(float);
    float* dsum  = (float*)(ws + off); off += sizeof(float);
    size_t zbytes = (size_t)((char*)(dsum + 1) - zbase);

    hipMemsetAsync(zbase, 0, zbytes, stream);
    scan_kernel<<<NB, 256, 0, stream>>>(x, A, Bm, Wsel, bsel, gamma, beta, H, musig);
    y_stats_kernel<<<NB * CHUNKS, 256, 0, stream>>>(H, x, Cm, Dm, gamma, beta, musig,
                                                    SY, SYY, meanx, nsum, dsum, out);
    finalize_kernel<<<1, 256, 0, stream>>>(Wsel, bsel, meanx, SY, SYY, nsum, dsum, out);
}